// Round 2
// baseline (1476.985 us; speedup 1.0000x reference)
//
#include <hip/hip_runtime.h>
#include <math.h>

#define BB 8
#define CC 128
#define NN 2048
#define KK 10
#define TWO_CC 256

// ---------------- squared column norms in f64: xx[b*N+n] = sum_c h[b,c,n]^2 ----------------
__global__ __launch_bounds__(256) void k_xx(const float* __restrict__ h, double* __restrict__ xx) {
    int t = blockIdx.x * 256 + threadIdx.x;
    if (t >= BB * NN) return;
    int b = t / NN, n = t % NN;
    const float* p = h + (size_t)b * CC * NN + n;
    double s = 0.0;
#pragma unroll
    for (int c = 0; c < CC; ++c) {
        double v = (double)p[(size_t)c * NN];
        s += v * v;
    }
    xx[t] = s;
}

// ---------------- distance tile, f64 accumulate: pd[n,m] = 2*sum_c h[c,n]h[c,m] - xx[n] - xx[m] ----------------
__global__ __launch_bounds__(256) void k_dist(const float* __restrict__ h, const double* __restrict__ xx,
                                              double* __restrict__ pd, int b) {
    __shared__ float As[64][65];
    __shared__ float Bs[64][65];
    int n0 = blockIdx.y * 64, m0 = blockIdx.x * 64;
    const float* A = h + (size_t)b * CC * NN;
    int tid = threadIdx.x;
    int tx = tid & 15, ty = tid >> 4;
    double acc[4][4] = {};
    for (int c0 = 0; c0 < CC; c0 += 64) {
        for (int i = tid; i < 64 * 64; i += 256) {
            int j = i & 63, c = i >> 6;
            As[c][j] = A[(size_t)(c0 + c) * NN + n0 + j];
            Bs[c][j] = A[(size_t)(c0 + c) * NN + m0 + j];
        }
        __syncthreads();
        for (int c = 0; c < 64; ++c) {
            double a[4], bb[4];
#pragma unroll
            for (int q = 0; q < 4; ++q) {
                a[q] = (double)As[c][ty * 4 + q];
                bb[q] = (double)Bs[c][tx * 4 + q];
            }
#pragma unroll
            for (int i2 = 0; i2 < 4; ++i2)
#pragma unroll
                for (int j = 0; j < 4; ++j) acc[i2][j] += a[i2] * bb[j];
        }
        __syncthreads();
    }
    const double* xxb = xx + b * NN;
#pragma unroll
    for (int i2 = 0; i2 < 4; ++i2) {
        int n = n0 + ty * 4 + i2;
        double xn = xxb[n];
#pragma unroll
        for (int j = 0; j < 4; ++j) {
            int m = m0 + tx * 4 + j;
            pd[(size_t)n * NN + m] = 2.0 * acc[i2][j] - xn - xxb[m];
        }
    }
}

// ---------------- top-10 per row on f64 keys; ties -> smaller index (JAX semantics) ----------------
__global__ __launch_bounds__(256) void k_topk(const double* __restrict__ pd, int* __restrict__ idx, int b) {
    __shared__ double keys[NN];    // 16 KB
    __shared__ double rv[256];
    __shared__ int ri[256];
    int n = blockIdx.x;
    int tid = threadIdx.x;
    const double* row = pd + (size_t)n * NN;
    for (int m = tid; m < NN; m += 256) keys[m] = row[m];
    __syncthreads();
    for (int k = 0; k < KK; ++k) {
        double bv = -INFINITY;
        int bm = 0x7fffffff;
        for (int m = tid; m < NN; m += 256) {
            double v = keys[m];
            if (v > bv || (v == bv && m < bm)) { bv = v; bm = m; }
        }
        rv[tid] = bv; ri[tid] = bm;
        __syncthreads();
        for (int s = 128; s > 0; s >>= 1) {
            if (tid < s) {
                if (rv[tid + s] > rv[tid] || (rv[tid + s] == rv[tid] && ri[tid + s] < ri[tid])) {
                    rv[tid] = rv[tid + s]; ri[tid] = ri[tid + s];
                }
            }
            __syncthreads();
        }
        if (tid == 0) {
            int m = ri[0];
            keys[m] = -INFINITY;
            idx[((size_t)b * NN + n) * KK + k] = m;
        }
        __syncthreads();
    }
}

// ---------------- neighbor mean: M[b][n][c] = (1/K) sum_k h[b,c,idx[b,n,k]] ----------------
__global__ __launch_bounds__(128) void k_gather(const float* __restrict__ h, const int* __restrict__ idx,
                                                float* __restrict__ M) {
    int bn = blockIdx.x;
    int b = bn / NN;
    int c = threadIdx.x;
    const int* ip = idx + (size_t)bn * KK;
    const float* hb = h + (size_t)b * CC * NN + (size_t)c * NN;
    float s = 0.f;
#pragma unroll
    for (int k = 0; k < KK; ++k) s += hb[ip[k]];
    M[(size_t)bn * CC + c] = s * (1.f / KK);
}

// ---------------- y[b,o,n] = sum_c Wa[o,c]*M[b,n,c] + sum_c (Wb-Wa)[o,c]*h[b,c,n] + bias[o] ----------------
__global__ __launch_bounds__(256) void k_gemm(const float* __restrict__ M, const float* __restrict__ h,
                                              const float* __restrict__ W, const float* __restrict__ bias,
                                              float* __restrict__ y) {
    __shared__ float Ws[64][33];
    __shared__ float Xs[32][65];
    int b = blockIdx.z;
    int o0 = blockIdx.y * 64;
    int n0 = blockIdx.x * 64;
    int tid = threadIdx.x;
    int tx = tid & 15, ty = tid >> 4;
    float acc[4][4] = {};
    const float* Mb = M + (size_t)b * NN * CC;
    const float* hb = h + (size_t)b * CC * NN;

    // term 1: Wa x M
    for (int c0 = 0; c0 < CC; c0 += 32) {
        for (int i = tid; i < 64 * 32; i += 256) {
            int c = i & 31, o = i >> 5;
            Ws[o][c] = W[(size_t)(o0 + o) * TWO_CC + c0 + c];
        }
        for (int i = tid; i < 64 * 32; i += 256) {
            int c = i & 31, nn = i >> 5;
            Xs[c][nn] = Mb[(size_t)(n0 + nn) * CC + c0 + c];
        }
        __syncthreads();
        for (int c = 0; c < 32; ++c) {
            float a[4], bb[4];
#pragma unroll
            for (int q = 0; q < 4; ++q) { a[q] = Ws[ty * 4 + q][c]; bb[q] = Xs[c][tx * 4 + q]; }
#pragma unroll
            for (int i2 = 0; i2 < 4; ++i2)
#pragma unroll
                for (int j = 0; j < 4; ++j) acc[i2][j] += a[i2] * bb[j];
        }
        __syncthreads();
    }
    // term 2: (Wb - Wa) x h
    for (int c0 = 0; c0 < CC; c0 += 32) {
        for (int i = tid; i < 64 * 32; i += 256) {
            int c = i & 31, o = i >> 5;
            const float* wr = W + (size_t)(o0 + o) * TWO_CC;
            Ws[o][c] = wr[CC + c0 + c] - wr[c0 + c];
        }
        for (int i = tid; i < 64 * 32; i += 256) {
            int nn = i & 63, c = i >> 6;
            Xs[c][nn] = hb[(size_t)(c0 + c) * NN + n0 + nn];
        }
        __syncthreads();
        for (int c = 0; c < 32; ++c) {
            float a[4], bb[4];
#pragma unroll
            for (int q = 0; q < 4; ++q) { a[q] = Ws[ty * 4 + q][c]; bb[q] = Xs[c][tx * 4 + q]; }
#pragma unroll
            for (int i2 = 0; i2 < 4; ++i2)
#pragma unroll
                for (int j = 0; j < 4; ++j) acc[i2][j] += a[i2] * bb[j];
        }
        __syncthreads();
    }
#pragma unroll
    for (int i2 = 0; i2 < 4; ++i2) {
        int o = o0 + ty * 4 + i2;
        float bv = bias[o];
#pragma unroll
        for (int j = 0; j < 4; ++j) {
            int nn = n0 + tx * 4 + j;
            y[((size_t)b * CC + o) * NN + nn] = acc[i2][j] + bv;
        }
    }
}

// ---------------- per-(b,o) mean/var(ddof=1) over N, relu, optional residual ----------------
__global__ __launch_bounds__(256) void k_norm(const float* __restrict__ y, const float* __restrict__ res,
                                              float* __restrict__ out, int add_res) {
    int bo = blockIdx.x;
    const float* row = y + (size_t)bo * NN;
    float s = 0.f, s2 = 0.f;
    for (int n = threadIdx.x; n < NN; n += 256) {
        float v = row[n];
        s += v;
        s2 += v * v;
    }
#pragma unroll
    for (int off = 32; off > 0; off >>= 1) {
        s += __shfl_down(s, off, 64);
        s2 += __shfl_down(s2, off, 64);
    }
    __shared__ float ss[4], ss2[4];
    int wave = threadIdx.x >> 6, lane = threadIdx.x & 63;
    if (lane == 0) { ss[wave] = s; ss2[wave] = s2; }
    __syncthreads();
    if (threadIdx.x == 0) {
        float S = ss[0] + ss[1] + ss[2] + ss[3];
        float S2 = ss2[0] + ss2[1] + ss2[2] + ss2[3];
        float mean = S * (1.f / NN);
        float var = (S2 - S * mean) * (1.f / (NN - 1));
        ss[0] = mean;
        ss2[0] = rsqrtf(var + 1e-3f);
    }
    __syncthreads();
    float mean = ss[0], inv = ss2[0];
    for (int n = threadIdx.x; n < NN; n += 256) {
        float v = (row[n] - mean) * inv;
        v = fmaxf(v, 0.f);
        if (add_res) v += res[(size_t)bo * NN + n];
        out[(size_t)bo * NN + n] = v;
    }
}

extern "C" void kernel_launch(void* const* d_in, const int* in_sizes, int n_in,
                              void* d_out, int out_size, void* d_ws, size_t ws_size,
                              hipStream_t stream) {
    const float* x  = (const float*)d_in[0];
    const float* W1 = (const float*)d_in[1];
    const float* b1 = (const float*)d_in[2];
    const float* W2 = (const float*)d_in[3];
    const float* b2 = (const float*)d_in[4];
    float* out = (float*)d_out;

    // workspace carve (bytes), doubles first for alignment:
    char* ws = (char*)d_ws;
    double* pd = (double*)ws;                                   // 2048*2048 doubles = 33.55 MB (per-batch reuse)
    double* xx = (double*)(ws + (size_t)NN * NN * 8);           // 8*2048 doubles
    char* p = ws + (size_t)NN * NN * 8 + (size_t)BB * NN * 8;
    int* idx = (int*)p;                                         // 8*2048*10 ints
    p += (size_t)BB * NN * KK * 4;
    float* M = (float*)p;                                       // 8*2048*128 floats
    p += (size_t)BB * NN * CC * 4;
    float* y = (float*)p;                                       // 8*128*2048 floats
    p += (size_t)BB * CC * NN * 4;
    float* h1 = (float*)p;                                      // 8*128*2048 floats

    auto layer = [&](const float* hin, const float* Wt, const float* bt, float* hout, int add_res) {
        hipLaunchKernelGGL(k_xx, dim3((BB * NN) / 256), dim3(256), 0, stream, hin, xx);
        for (int b = 0; b < BB; ++b) {
            hipLaunchKernelGGL(k_dist, dim3(NN / 64, NN / 64), dim3(256), 0, stream, hin, xx, pd, b);
            hipLaunchKernelGGL(k_topk, dim3(NN), dim3(256), 0, stream, pd, idx, b);
        }
        hipLaunchKernelGGL(k_gather, dim3(BB * NN), dim3(CC), 0, stream, hin, idx, M);
        hipLaunchKernelGGL(k_gemm, dim3(NN / 64, CC / 64, BB), dim3(256), 0, stream, M, hin, Wt, bt, y);
        hipLaunchKernelGGL(k_norm, dim3(BB * CC), dim3(256), 0, stream, y, x, hout, add_res);
    };

    layer(x, W1, b1, h1, 0);
    layer(h1, W2, b2, out, 1);
}

// Round 3
// 1248.718 us; speedup vs baseline: 1.1828x; 1.1828x over previous
//
#include <hip/hip_runtime.h>
#include <math.h>

#define BB 8
#define CC 128
#define NN 2048
#define KK 10
#define TWO_CC 256

// exact-ranking comparator: larger key wins; ties -> smaller index (JAX semantics)
__device__ __forceinline__ void insert10(double (&LV)[10], int (&LI)[10], double v, int m) {
    if (v > LV[9] || (v == LV[9] && m < LI[9])) {
        LV[9] = v; LI[9] = m;
#pragma unroll
        for (int q = 9; q >= 1; --q) {
            bool sw = (LV[q] > LV[q - 1]) || (LV[q] == LV[q - 1] && LI[q] < LI[q - 1]);
            double tv = LV[q], tu = LV[q - 1];
            int iv = LI[q], iu = LI[q - 1];
            LV[q]     = sw ? tu : tv;
            LV[q - 1] = sw ? tv : tu;
            LI[q]     = sw ? iu : iv;
            LI[q - 1] = sw ? iv : iu;
        }
    }
}

// ---------------- squared column norms in f64 ----------------
__global__ __launch_bounds__(256) void k_xx(const float* __restrict__ h, double* __restrict__ xx) {
    int t = blockIdx.x * 256 + threadIdx.x;
    if (t >= BB * NN) return;
    int b = t / NN, n = t % NN;
    const float* p = h + (size_t)b * CC * NN + n;
    double s = 0.0;
#pragma unroll
    for (int c = 0; c < CC; ++c) {
        double v = (double)p[(size_t)c * NN];
        s += v * v;
    }
    xx[t] = s;
}

// ---------------- fused distance + top-10 ----------------
// block: 32 rows (n0..n0+31) of batch b; 256 threads; tx=t&15 (4 cols each), ty=t>>4 (2 rows each)
__global__ __launch_bounds__(256) void k_knn(const float* __restrict__ h, const double* __restrict__ xxg,
                                             int* __restrict__ idxout) {
    __shared__ __align__(16) char smem[49664];
    float* At2 = (float*)smem;                 // [128][32] fp32, k-major
    float* Bsm = (float*)(smem + 16384);       // [128][64] fp32, k-major
    double* xsd = (double*)(smem + 49152);     // [64]
    double* mgV = (double*)(smem + 16384);     // merge overlay on Bsm: [32][8][10] f64
    int*    mgI = (int*)(smem + 36864);        // [32][8][10] int

    int t = threadIdx.x;
    int tx = t & 15, ty = t >> 4;
    int b = blockIdx.y;
    int n0 = blockIdx.x * 32;
    const float* hb = h + (size_t)b * CC * NN;

    // stage A-tile transposed: At2[c][j] = h[b][c][n0+j]
#pragma unroll
    for (int i = 0; i < 4; ++i) {
        int G = t + 256 * i;            // 0..1023 float4-groups
        int c = G >> 3, u = G & 7;
        float4 v = *(const float4*)(hb + (size_t)c * NN + n0 + u * 4);
        *(float4*)(At2 + c * 32 + u * 4) = v;
    }

    double LV[2][10]; int LI[2][10];
#pragma unroll
    for (int rr = 0; rr < 2; ++rr)
#pragma unroll
        for (int q = 0; q < 10; ++q) { LV[rr][q] = -1.0e300; LI[rr][q] = 0x7FFFFFFF; }

    for (int mt = 0; mt < 32; ++mt) {
        int m0 = mt * 64;
        __syncthreads();                 // Bsm free (also covers At2 staging on mt=0)
#pragma unroll
        for (int i = 0; i < 8; ++i) {
            int G = t + 256 * i;        // 0..2047 float4-groups
            int c = G >> 4, u = G & 15;
            float4 v = *(const float4*)(hb + (size_t)c * NN + m0 + u * 4);
            *(float4*)(Bsm + c * 64 + u * 4) = v;
        }
        if (t < 64) xsd[t] = xxg[b * NN + m0 + t];
        __syncthreads();

        double acc[2][4] = {};
#pragma unroll 2
        for (int k = 0; k < 128; ++k) {
            float2 af = *(const float2*)(At2 + k * 32 + 2 * ty);
            float4 bf = *(const float4*)(Bsm + k * 64 + 4 * tx);
            double a0 = (double)af.x, a1 = (double)af.y;
            double b0 = (double)bf.x, b1 = (double)bf.y, b2 = (double)bf.z, b3 = (double)bf.w;
            acc[0][0] += a0 * b0; acc[0][1] += a0 * b1; acc[0][2] += a0 * b2; acc[0][3] += a0 * b3;
            acc[1][0] += a1 * b0; acc[1][1] += a1 * b1; acc[1][2] += a1 * b2; acc[1][3] += a1 * b3;
        }
#pragma unroll
        for (int rr = 0; rr < 2; ++rr)
#pragma unroll
            for (int j = 0; j < 4; ++j) {
                double v = 2.0 * acc[rr][j] - xsd[4 * tx + j];
                insert10(LV[rr], LI[rr], v, m0 + 4 * tx + j);
            }
    }

    // hierarchical merge across tx: 16 -> 8 -> 4 -> 2 -> 1 lists per row
    for (int p = 0; p < 4; ++p) {
        int span = 1 << p;
        __syncthreads();
        bool act = (tx & (span - 1)) == 0;
        int g = tx >> p;
        if (act && (g & 1)) {
            int slot = g >> 1;
#pragma unroll
            for (int rr = 0; rr < 2; ++rr) {
                int base = ((2 * ty + rr) * 8 + slot) * 10;
#pragma unroll
                for (int q = 0; q < 10; ++q) { mgV[base + q] = LV[rr][q]; mgI[base + q] = LI[rr][q]; }
            }
        }
        __syncthreads();
        if (act && !(g & 1)) {
            int slot = g >> 1;
#pragma unroll
            for (int rr = 0; rr < 2; ++rr) {
                int base = ((2 * ty + rr) * 8 + slot) * 10;
#pragma unroll
                for (int q = 0; q < 10; ++q) insert10(LV[rr], LI[rr], mgV[base + q], mgI[base + q]);
            }
        }
    }
    if (tx == 0) {
#pragma unroll
        for (int rr = 0; rr < 2; ++rr) {
            int n = n0 + 2 * ty + rr;
            int* op = idxout + ((size_t)b * NN + n) * KK;
#pragma unroll
            for (int q = 0; q < 10; ++q) op[q] = LI[rr][q];
        }
    }
}

// ---------------- transpose: ht[b][n][c] = h[b][c][n] ----------------
__global__ __launch_bounds__(256) void k_tr(const float* __restrict__ h, float* __restrict__ ht) {
    __shared__ float tile[32][33];
    int b = blockIdx.z, c0 = blockIdx.y * 32, n0 = blockIdx.x * 32;
    int tx = threadIdx.x & 31, tyy = threadIdx.x >> 5;
    const float* hb = h + (size_t)b * CC * NN;
#pragma unroll
    for (int i = 0; i < 4; ++i)
        tile[tyy + i * 8][tx] = hb[(size_t)(c0 + tyy + i * 8) * NN + n0 + tx];
    __syncthreads();
    float* htb = ht + (size_t)b * NN * CC;
#pragma unroll
    for (int i = 0; i < 4; ++i)
        htb[(size_t)(n0 + tyy + i * 8) * CC + c0 + tx] = tile[tx][tyy + i * 8];
}

// ---------------- coalesced neighbor mean from ht ----------------
__global__ __launch_bounds__(256) void k_gather(const float* __restrict__ ht, const int* __restrict__ idx,
                                                float* __restrict__ M) {
    int bn = blockIdx.x * 2 + (threadIdx.x >> 7);
    int c = threadIdx.x & 127;
    int b = bn >> 11;
    const int* ip = idx + (size_t)bn * KK;
    const float* hb = ht + (size_t)b * NN * CC;
    float s = 0.f;
#pragma unroll
    for (int k = 0; k < KK; ++k) s += hb[(size_t)ip[k] * CC + c];
    M[(size_t)bn * CC + c] = s * (1.f / KK);
}

// ---------------- y = Wa*M + (Wb-Wa)*h + bias ----------------
__global__ __launch_bounds__(256) void k_gemm(const float* __restrict__ M, const float* __restrict__ h,
                                              const float* __restrict__ W, const float* __restrict__ bias,
                                              float* __restrict__ y) {
    __shared__ float Ws[64][33];
    __shared__ float Xs[32][65];
    int b = blockIdx.z;
    int o0 = blockIdx.y * 64;
    int n0 = blockIdx.x * 64;
    int tid = threadIdx.x;
    int tx = tid & 15, ty = tid >> 4;
    float acc[4][4] = {};
    const float* Mb = M + (size_t)b * NN * CC;
    const float* hb = h + (size_t)b * CC * NN;

    for (int c0 = 0; c0 < CC; c0 += 32) {
        for (int i = tid; i < 64 * 32; i += 256) {
            int c = i & 31, o = i >> 5;
            Ws[o][c] = W[(size_t)(o0 + o) * TWO_CC + c0 + c];
        }
        for (int i = tid; i < 64 * 32; i += 256) {
            int c = i & 31, nn = i >> 5;
            Xs[c][nn] = Mb[(size_t)(n0 + nn) * CC + c0 + c];
        }
        __syncthreads();
        for (int c = 0; c < 32; ++c) {
            float a[4], bb[4];
#pragma unroll
            for (int q = 0; q < 4; ++q) { a[q] = Ws[ty * 4 + q][c]; bb[q] = Xs[c][tx * 4 + q]; }
#pragma unroll
            for (int i2 = 0; i2 < 4; ++i2)
#pragma unroll
                for (int j = 0; j < 4; ++j) acc[i2][j] += a[i2] * bb[j];
        }
        __syncthreads();
    }
    for (int c0 = 0; c0 < CC; c0 += 32) {
        for (int i = tid; i < 64 * 32; i += 256) {
            int c = i & 31, o = i >> 5;
            const float* wr = W + (size_t)(o0 + o) * TWO_CC;
            Ws[o][c] = wr[CC + c0 + c] - wr[c0 + c];
        }
        for (int i = tid; i < 64 * 32; i += 256) {
            int nn = i & 63, c = i >> 6;
            Xs[c][nn] = hb[(size_t)(c0 + c) * NN + n0 + nn];
        }
        __syncthreads();
        for (int c = 0; c < 32; ++c) {
            float a[4], bb[4];
#pragma unroll
            for (int q = 0; q < 4; ++q) { a[q] = Ws[ty * 4 + q][c]; bb[q] = Xs[c][tx * 4 + q]; }
#pragma unroll
            for (int i2 = 0; i2 < 4; ++i2)
#pragma unroll
                for (int j = 0; j < 4; ++j) acc[i2][j] += a[i2] * bb[j];
        }
        __syncthreads();
    }
#pragma unroll
    for (int i2 = 0; i2 < 4; ++i2) {
        int o = o0 + ty * 4 + i2;
        float bv = bias[o];
#pragma unroll
        for (int j = 0; j < 4; ++j)
            y[((size_t)b * CC + o) * NN + n0 + tx * 4 + j] = acc[i2][j] + bv;
    }
}

// ---------------- per-(b,o) mean/var(ddof=1), relu, optional residual ----------------
__global__ __launch_bounds__(256) void k_norm(const float* __restrict__ y, const float* __restrict__ res,
                                              float* __restrict__ out, int add_res) {
    int bo = blockIdx.x;
    const float* row = y + (size_t)bo * NN;
    float s = 0.f, s2 = 0.f;
    for (int n = threadIdx.x; n < NN; n += 256) {
        float v = row[n];
        s += v;
        s2 += v * v;
    }
#pragma unroll
    for (int off = 32; off > 0; off >>= 1) {
        s += __shfl_down(s, off, 64);
        s2 += __shfl_down(s2, off, 64);
    }
    __shared__ float ss[4], ss2[4];
    int wave = threadIdx.x >> 6, lane = threadIdx.x & 63;
    if (lane == 0) { ss[wave] = s; ss2[wave] = s2; }
    __syncthreads();
    if (threadIdx.x == 0) {
        float S = ss[0] + ss[1] + ss[2] + ss[3];
        float S2 = ss2[0] + ss2[1] + ss2[2] + ss2[3];
        float mean = S * (1.f / NN);
        float var = (S2 - S * mean) * (1.f / (NN - 1));
        ss[0] = mean;
        ss2[0] = rsqrtf(var + 1e-3f);
    }
    __syncthreads();
    float mean = ss[0], inv = ss2[0];
    for (int n = threadIdx.x; n < NN; n += 256) {
        float v = (row[n] - mean) * inv;
        v = fmaxf(v, 0.f);
        if (add_res) v += res[(size_t)bo * NN + n];
        out[(size_t)bo * NN + n] = v;
    }
}

extern "C" void kernel_launch(void* const* d_in, const int* in_sizes, int n_in,
                              void* d_out, int out_size, void* d_ws, size_t ws_size,
                              hipStream_t stream) {
    const float* x  = (const float*)d_in[0];
    const float* W1 = (const float*)d_in[1];
    const float* b1 = (const float*)d_in[2];
    const float* W2 = (const float*)d_in[3];
    const float* b2 = (const float*)d_in[4];
    float* out = (float*)d_out;

    char* wsb = (char*)d_ws;
    double* xx = (double*)wsb;                          // 8*2048 f64          = 131072 B
    char* p = wsb + (size_t)BB * NN * 8;
    int* idx = (int*)p;       p += (size_t)BB * NN * KK * 4;    // 655360 B
    float* ht = (float*)p;    p += (size_t)BB * NN * CC * 4;    // 8 MB
    float* M  = (float*)p;    p += (size_t)BB * NN * CC * 4;    // 8 MB
    float* y  = (float*)p;    p += (size_t)BB * CC * NN * 4;    // 8 MB
    float* h1 = (float*)p;                                      // 8 MB

    auto layer = [&](const float* hin, const float* Wt, const float* bt, float* hout, int add_res) {
        hipLaunchKernelGGL(k_xx, dim3((BB * NN) / 256), dim3(256), 0, stream, hin, xx);
        hipLaunchKernelGGL(k_tr, dim3(NN / 32, CC / 32, BB), dim3(256), 0, stream, hin, ht);
        hipLaunchKernelGGL(k_knn, dim3(NN / 32, BB), dim3(256), 0, stream, hin, xx, idx);
        hipLaunchKernelGGL(k_gather, dim3(BB * NN / 2), dim3(256), 0, stream, ht, idx, M);
        hipLaunchKernelGGL(k_gemm, dim3(NN / 64, CC / 64, BB), dim3(256), 0, stream, M, hin, Wt, bt, y);
        hipLaunchKernelGGL(k_norm, dim3(BB * CC), dim3(256), 0, stream, y, x, hout, add_res);
    };

    layer(x, W1, b1, h1, 0);
    layer(h1, W2, b2, out, 1);
}